// Round 4
// baseline (33.148 us; speedup 1.0000x reference)
//
#include <hip/hip_runtime.h>

#define RR 300
#define NCLS 37
#define COUT 36
#define NB 32
#define NSTRIP 5           // ceil(300/64)
#define CAP 304
#define SCORE_THR_C 0.1f
#define NMS_THR_C 0.4f

// One wave (64 lanes) handles one (b,c) pair; 2 waves per block; 576 blocks.
// All NMS state fits one wave: nv valid candidates (typ. ~20), 5x u64 bitmasks.
__global__ __launch_bounds__(128) void det_wave_kernel(
    const float* __restrict__ rois,
    const float* __restrict__ pred,
    const float* __restrict__ scr,
    const float* __restrict__ iminfo,
    float* __restrict__ out)
{
#pragma clang fp contract(off)
    const int bid  = blockIdx.x;
    const int wid  = threadIdx.x >> 6;
    const int lane = threadIdx.x & 63;
    // XCD-aware bijective swizzle: 576 blocks = 8 XCDs * 72; each XCD gets 4
    // whole batches (144 bc pairs) -> pred/scores lines shared in its L2.
    const int bc   = (bid & 7) * 144 + (bid >> 3) * 2 + wid;
    const int b    = bc / COUT;
    const int c    = bc % COUT;
    const int cls  = c + 1;

    __shared__ float4             cbx[2][CAP];          // compacted->sorted boxes
    __shared__ float              csa[2][CAP];          // scores, then areas
    __shared__ int                cor[2][CAP];          // original roi index
    __shared__ unsigned long long msk[2][CAP][NSTRIP];  // suppression rows
    __shared__ unsigned char      keepG[2][CAP];        // keep per original roi

    // ---- load (coalesced rois; pred/scores strided as the layout dictates) ----
    float4 ro[NSTRIP], pp[NSTRIP];
    float  ss[NSTRIP];
    #pragma unroll
    for (int t = 0; t < NSTRIP; ++t) {
        const int r = lane + 64 * t;
        const int kg = lane + 64 * t;
        if (kg < CAP) keepG[wid][kg] = 0;
        if (r < RR) {
            ro[t] = *reinterpret_cast<const float4*>(rois + (size_t)(b * RR + r) * 4);
            pp[t] = *reinterpret_cast<const float4*>(pred + (size_t)(b * RR + r) * (4 * NCLS) + 4 * cls);
            ss[t] = scr[(size_t)(b * RR + r) * NCLS + cls];
        } else {
            ro[t] = make_float4(0.f, 0.f, 0.f, 0.f);
            pp[t] = make_float4(0.f, 0.f, 0.f, 0.f);
            ss[t] = 0.f;
        }
    }
    const float Hm1 = iminfo[b * 3 + 0] - 1.0f;
    const float Wm1 = iminfo[b * 3 + 1] - 1.0f;
    const float scl = iminfo[2];   // im_info[0, 2] for ALL batches (per reference)

    // ---- decode (exact f32 expression order as reference) ----
    float4 bx[NSTRIP];
    bool   vv[NSTRIP];
    #pragma unroll
    for (int t = 0; t < NSTRIP; ++t) {
        const int r = lane + 64 * t;
        float w  = ro[t].z - ro[t].x + 1.0f;
        float h  = ro[t].w - ro[t].y + 1.0f;
        float cx = ro[t].x + 0.5f * w;
        float cy = ro[t].y + 0.5f * h;
        float dx = pp[t].x * 0.1f;
        float dy = pp[t].y * 0.1f;
        float dw = pp[t].z * 0.2f;
        float dh = pp[t].w * 0.2f;
        float pcx = dx * w + cx;
        float pcy = dy * h + cy;
        float pw  = expf(dw) * w;
        float ph  = expf(dh) * h;
        bx[t].x = fminf(fmaxf(pcx - 0.5f * pw, 0.0f), Wm1) / scl;
        bx[t].y = fminf(fmaxf(pcy - 0.5f * ph, 0.0f), Hm1) / scl;
        bx[t].z = fminf(fmaxf(pcx + 0.5f * pw, 0.0f), Wm1) / scl;
        bx[t].w = fminf(fmaxf(pcy + 0.5f * ph, 0.0f), Hm1) / scl;
        vv[t] = (r < RR) && (ss[t] > SCORE_THR_C);
    }

    // ---- wave compaction: valid set is a prefix of the stable sort ----
    const unsigned long long lmask = (1ull << lane) - 1ull;
    unsigned long long bal[NSTRIP];
    int pos[NSTRIP];
    #pragma unroll
    for (int t = 0; t < NSTRIP; ++t) bal[t] = __ballot(vv[t]);
    int acc = 0;
    #pragma unroll
    for (int t = 0; t < NSTRIP; ++t) {
        pos[t] = acc + __popcll(bal[t] & lmask);
        acc   += __popcll(bal[t]);
    }
    const int nv = acc;
    #pragma unroll
    for (int t = 0; t < NSTRIP; ++t) {
        if (vv[t]) {
            csa[wid][pos[t]] = ss[t];
            cbx[wid][pos[t]] = bx[t];
            cor[wid][pos[t]] = lane + 64 * t;
        }
    }
    __syncthreads();

    // ---- stable descending rank among nv candidates (broadcast LDS reads) ----
    bool   act[NSTRIP];
    float4 myB[NSTRIP];
    float  myS[NSTRIP], myA[NSTRIP];
    int    myO[NSTRIP], myR[NSTRIP];
    #pragma unroll
    for (int t = 0; t < NSTRIP; ++t) {
        const int p = lane + 64 * t;
        act[t] = (p < nv);
        myR[t] = 0;
        if (act[t]) {
            myB[t] = cbx[wid][p];
            myS[t] = csa[wid][p];
            myO[t] = cor[wid][p];
            myA[t] = (myB[t].z - myB[t].x) * (myB[t].w - myB[t].y);
        }
    }
    for (int q = 0; q < nv; ++q) {
        const float sq = csa[wid][q];
        const int   oq = cor[wid][q];
        #pragma unroll
        for (int t = 0; t < NSTRIP; ++t)
            if (act[t])
                myR[t] += (int)(sq > myS[t]) + ((int)(sq == myS[t]) & (int)(oq < myO[t]));
    }
    __syncthreads();   // rank-phase reads complete before re-scatter

    // ---- scatter into sorted slots (csa now holds AREAS) ----
    #pragma unroll
    for (int t = 0; t < NSTRIP; ++t) {
        if (act[t]) {
            cbx[wid][myR[t]] = myB[t];
            cor[wid][myR[t]] = myO[t];
            csa[wid][myR[t]] = myA[t];
        }
    }
    __syncthreads();

    // ---- re-read own sorted slot; build suppression rows ----
    #pragma unroll
    for (int t = 0; t < NSTRIP; ++t) {
        if (act[t]) {
            const int p = lane + 64 * t;
            myB[t] = cbx[wid][p];
            myA[t] = csa[wid][p];
        }
    }
    for (int ws = 0; ws < NSTRIP; ++ws) {
        unsigned long long seg[NSTRIP];
        #pragma unroll
        for (int t = 0; t < NSTRIP; ++t) seg[t] = 0ull;
        const int j0 = ws * 64;
        int jn = nv - j0;
        if (jn > 64) jn = 64;
        for (int j2 = 0; j2 < jn; ++j2) {
            const int j = j0 + j2;
            const float4 bj = cbx[wid][j];   // broadcast
            const float  aj = csa[wid][j];   // broadcast (area)
            #pragma unroll
            for (int t = 0; t < NSTRIP; ++t) {
                if (act[t]) {
                    const int p = lane + 64 * t;
                    float lx = fmaxf(myB[t].x, bj.x);
                    float ly = fmaxf(myB[t].y, bj.y);
                    float rx = fminf(myB[t].z, bj.z);
                    float ry = fminf(myB[t].w, bj.w);
                    float iw = fmaxf(rx - lx, 0.0f);
                    float ih = fmaxf(ry - ly, 0.0f);
                    float inter = iw * ih;
                    float den = myA[t] + aj - inter + 1e-12f;  // ref expression order
                    float iou = inter / den;
                    if ((iou > NMS_THR_C) & (j > p)) seg[t] |= (1ull << j2);
                }
            }
        }
        #pragma unroll
        for (int t = 0; t < NSTRIP; ++t)
            if (act[t]) msk[wid][lane + 64 * t][ws] = seg[t];
    }
    __syncthreads();

    // ---- greedy scan, wave-uniform (all lanes redundantly; LDS broadcast) ----
    unsigned long long lv[NSTRIP], kb[NSTRIP];
    #pragma unroll
    for (int w = 0; w < NSTRIP; ++w) {
        const int lo = w * 64;
        lv[w] = (nv >= lo + 64) ? ~0ull : ((nv <= lo) ? 0ull : ((~0ull) >> (64 - (nv - lo))));
        kb[w] = 0ull;
    }
    int top = -1;
    for (;;) {
        int i = -1;
        #pragma unroll
        for (int w = 0; w < NSTRIP; ++w) {
            if (i < 0 && lv[w]) {
                const int tz = __builtin_ctzll(lv[w]);
                lv[w] &= lv[w] - 1ull;          // clear lowest set bit
                kb[w] |= (1ull << tz);
                i = w * 64 + tz;
            }
        }
        if (i < 0) break;
        if (top < 0) top = i;
        #pragma unroll
        for (int w = 0; w < NSTRIP; ++w) lv[w] &= ~msk[wid][i][w];
    }

    // ---- scatter keep to original roi index ----
    #pragma unroll
    for (int t = 0; t < NSTRIP; ++t) {
        if (act[t]) {
            const int p = lane + 64 * t;
            const bool k = (c == 0) ? (p == top) : (((kb[t] >> lane) & 1ull) != 0ull);
            if (k) keepG[wid][cor[wid][p]] = 1;
        }
    }
    __syncthreads();

    // ---- output from registers ----
    #pragma unroll
    for (int t = 0; t < NSTRIP; ++t) {
        const int r = lane + 64 * t;
        if (r < RR) {
            const float k = keepG[wid][r] ? 1.0f : 0.0f;
            const size_t base = (((size_t)b * COUT + c) * RR + r) * 5;
            out[base + 0] = fmaxf(bx[t].x, 0.0f) * k;
            out[base + 1] = fmaxf(bx[t].y, 0.0f) * k;
            out[base + 2] = fmaxf(bx[t].z, 0.0f) * k;
            out[base + 3] = fmaxf(bx[t].w, 0.0f) * k;
            out[base + 4] = fmaxf(ss[t],  0.0f) * k;
        }
    }
}

extern "C" void kernel_launch(void* const* d_in, const int* in_sizes, int n_in,
                              void* d_out, int out_size, void* d_ws, size_t ws_size,
                              hipStream_t stream) {
    const float* rois   = (const float*)d_in[0];
    const float* pred   = (const float*)d_in[1];
    const float* scores = (const float*)d_in[2];
    const float* iminfo = (const float*)d_in[3];
    float* out = (float*)d_out;
    det_wave_kernel<<<dim3(576), dim3(128), 0, stream>>>(rois, pred, scores, iminfo, out);
}

// Round 5
// 30.937 us; speedup vs baseline: 1.0715x; 1.0715x over previous
//
#include <hip/hip_runtime.h>

#define RR 300
#define NCLS 37
#define COUT 36
#define NSTRIP 5
#define CAP 304
#define SCORE_THR_C 0.1f
#define NMS_THR_C 0.4f

// One wave per (b,c) pair. 4 waves/block, 288 blocks = 1152 pairs.
// No __syncthreads: each wave uses its own LDS slice; CDNA waves are lockstep
// and the compiler inserts lgkmcnt waits for LDS dependencies.
__global__ __launch_bounds__(256) void det_wave2_kernel(
    const float* __restrict__ rois,
    const float* __restrict__ pred,
    const float* __restrict__ scr,
    const float* __restrict__ iminfo,
    float* __restrict__ out)
{
#pragma clang fp contract(off)
    const int bid  = blockIdx.x;
    const int wid  = threadIdx.x >> 6;
    const int lane = threadIdx.x & 63;
    // XCD-aware bijective swizzle: 288 blocks = 8 XCDs * 36; each XCD owns 4
    // whole batches (144 pairs) -> pred/scores lines shared in its L2.
    const int bc   = (bid & 7) * 144 + (bid >> 3) * 4 + wid;
    const int b    = bc / COUT;
    const int c    = bc % COUT;
    const int cls  = c + 1;

    __shared__ uint2  cpk[4][CAP];   // compact order: (score bits, orig r)
    __shared__ float4 sbx[4][CAP];   // rank order: boxes
    __shared__ int    sog[4][CAP];   // rank order: orig r

    // ---- gather inputs (L2-hot in steady state via swizzle) ----
    float4 ro[NSTRIP], pp[NSTRIP];
    float  ss[NSTRIP];
    #pragma unroll
    for (int t = 0; t < NSTRIP; ++t) {
        const int r = lane + 64 * t;
        if (r < RR) {
            ro[t] = *reinterpret_cast<const float4*>(rois + (size_t)(b * RR + r) * 4);
            pp[t] = *reinterpret_cast<const float4*>(pred + (size_t)(b * RR + r) * (4 * NCLS) + 4 * cls);
            ss[t] = scr[(size_t)(b * RR + r) * NCLS + cls];
        } else {
            ro[t] = make_float4(0.f, 0.f, 0.f, 0.f);
            pp[t] = make_float4(0.f, 0.f, 0.f, 0.f);
            ss[t] = 0.f;
        }
    }
    const float Hm1 = iminfo[b * 3 + 0] - 1.0f;
    const float Wm1 = iminfo[b * 3 + 1] - 1.0f;
    const float scl = iminfo[2];   // im_info[0, 2] for ALL batches (per reference)

    // ---- decode (exact f32 expression order as reference) ----
    float4 bx[NSTRIP];
    bool   vv[NSTRIP];
    #pragma unroll
    for (int t = 0; t < NSTRIP; ++t) {
        const int r = lane + 64 * t;
        float w  = ro[t].z - ro[t].x + 1.0f;
        float h  = ro[t].w - ro[t].y + 1.0f;
        float cx = ro[t].x + 0.5f * w;
        float cy = ro[t].y + 0.5f * h;
        float dx = pp[t].x * 0.1f;
        float dy = pp[t].y * 0.1f;
        float dw = pp[t].z * 0.2f;
        float dh = pp[t].w * 0.2f;
        float pcx = dx * w + cx;
        float pcy = dy * h + cy;
        float pw  = expf(dw) * w;
        float ph  = expf(dh) * h;
        bx[t].x = fminf(fmaxf(pcx - 0.5f * pw, 0.0f), Wm1) / scl;
        bx[t].y = fminf(fmaxf(pcy - 0.5f * ph, 0.0f), Hm1) / scl;
        bx[t].z = fminf(fmaxf(pcx + 0.5f * pw, 0.0f), Wm1) / scl;
        bx[t].w = fminf(fmaxf(pcy + 0.5f * ph, 0.0f), Hm1) / scl;
        vv[t] = (r < RR) && (ss[t] > SCORE_THR_C);
    }

    // ---- compaction positions (wave-local ballots) ----
    const unsigned long long lmask = (1ull << lane) - 1ull;
    int pos[NSTRIP];
    int acc = 0;
    #pragma unroll
    for (int t = 0; t < NSTRIP; ++t) {
        const unsigned long long balt = __ballot(vv[t]);
        pos[t] = acc + __popcll(balt & lmask);
        acc   += __popcll(balt);
    }
    const int nv = __builtin_amdgcn_readfirstlane(acc);   // scalar -> uniform branches

    #pragma unroll
    for (int t = 0; t < NSTRIP; ++t)
        if (vv[t]) cpk[wid][pos[t]] = make_uint2(__float_as_uint(ss[t]),
                                                 (unsigned)(lane + 64 * t));

    // ---- stable descending rank (matches argsort(-s) prefix; ties by orig) ----
    int myR[NSTRIP];
    #pragma unroll
    for (int t = 0; t < NSTRIP; ++t) myR[t] = 0;
    for (int q = 0; q < nv; ++q) {
        const uint2 pk = cpk[wid][q];          // wave-uniform broadcast read
        const float sq = __uint_as_float(pk.x);
        const int   oq = (int)pk.y;
        #pragma unroll
        for (int t = 0; t < NSTRIP; ++t) {
            if (64 * t < RR && vv[t]) {
                const int r = lane + 64 * t;
                myR[t] += (int)(sq > ss[t]) + ((int)(sq == ss[t]) & (int)(oq < r));
            }
        }
    }

    // ---- scatter into rank slots (ranks are a permutation of [0,nv)) ----
    #pragma unroll
    for (int t = 0; t < NSTRIP; ++t) {
        if (vv[t]) {
            sbx[wid][myR[t]] = bx[t];
            sog[wid][myR[t]] = lane + 64 * t;
        }
    }

    // ---- reload sorted candidates: lane j holds sorted cand j (+64t) ----
    float4 sb[NSTRIP];
    float  sa[NSTRIP];
    #pragma unroll
    for (int t = 0; t < NSTRIP; ++t) {
        const int p = lane + 64 * t;
        if (64 * t < nv && p < nv) {
            sb[t] = sbx[wid][p];
            sa[t] = (sb[t].z - sb[t].x) * (sb[t].w - sb[t].y);
        } else {
            sb[t] = make_float4(0.f, 0.f, 0.f, 0.f);
            sa[t] = 0.f;
        }
    }

    // ---- greedy NMS scan, on-the-fly IoU (no mask matrix) ----
    unsigned long long live[NSTRIP], keepb[NSTRIP];
    #pragma unroll
    for (int t = 0; t < NSTRIP; ++t) {
        const int lo = 64 * t;
        live[t] = (nv >= lo + 64) ? ~0ull : ((nv <= lo) ? 0ull : ((~0ull) >> (64 - (nv - lo))));
        keepb[t] = 0ull;
    }
    int top_orig = -1;
    for (;;) {
        int p = -1;
        #pragma unroll
        for (int t = 0; t < NSTRIP; ++t)
            if (p < 0 && live[t]) p = 64 * t + __builtin_ctzll(live[t]);
        if (p < 0) break;

        const float4 pb = sbx[wid][p];                      // broadcast
        const float  pa = (pb.z - pb.x) * (pb.w - pb.y);
        if (top_orig < 0) top_orig = sog[wid][p];

        const int tp = p >> 6, bp = p & 63;
        #pragma unroll
        for (int t = 0; t < NSTRIP; ++t) {
            if (t == tp) { keepb[t] |= 1ull << bp; live[t] &= ~(1ull << bp); }
        }

        #pragma unroll
        for (int t = 0; t < NSTRIP; ++t) {
            if (64 * t < nv) {                               // uniform guard
                const int j = lane + 64 * t;
                float lx = fmaxf(pb.x, sb[t].x);
                float ly = fmaxf(pb.y, sb[t].y);
                float rx = fminf(pb.z, sb[t].z);
                float ry = fminf(pb.w, sb[t].w);
                float iw = fmaxf(rx - lx, 0.0f);
                float ih = fmaxf(ry - ly, 0.0f);
                float inter = iw * ih;
                float den = pa + sa[t] - inter + 1e-12f;     // ref expression order
                float iou = inter / den;
                const unsigned long long m = __ballot((iou > NMS_THR_C) && (j > p));
                live[t] &= ~m;
            }
        }
    }

    // ---- output: each thread owns its r's keep bit (its own rank) ----
    #pragma unroll
    for (int t = 0; t < NSTRIP; ++t) {
        const int r = lane + 64 * t;
        if (r < RR) {
            bool k;
            if (c == 0) {
                k = (r == top_orig);
            } else if (vv[t]) {
                const int w = myR[t] >> 6, bq = myR[t] & 63;
                unsigned long long kw = keepb[0];
                if (w == 1) kw = keepb[1];
                else if (w == 2) kw = keepb[2];
                else if (w == 3) kw = keepb[3];
                else if (w == 4) kw = keepb[4];
                k = ((kw >> bq) & 1ull) != 0ull;
            } else {
                k = false;
            }
            const float kf = k ? 1.0f : 0.0f;
            const size_t base = (((size_t)b * COUT + c) * RR + r) * 5;
            out[base + 0] = fmaxf(bx[t].x, 0.0f) * kf;
            out[base + 1] = fmaxf(bx[t].y, 0.0f) * kf;
            out[base + 2] = fmaxf(bx[t].z, 0.0f) * kf;
            out[base + 3] = fmaxf(bx[t].w, 0.0f) * kf;
            out[base + 4] = fmaxf(ss[t],  0.0f) * kf;
        }
    }
}

extern "C" void kernel_launch(void* const* d_in, const int* in_sizes, int n_in,
                              void* d_out, int out_size, void* d_ws, size_t ws_size,
                              hipStream_t stream) {
    const float* rois   = (const float*)d_in[0];
    const float* pred   = (const float*)d_in[1];
    const float* scores = (const float*)d_in[2];
    const float* iminfo = (const float*)d_in[3];
    float* out = (float*)d_out;
    det_wave2_kernel<<<dim3(288), dim3(256), 0, stream>>>(rois, pred, scores, iminfo, out);
}